// Round 18
// baseline (155.518 us; speedup 1.0000x reference)
//
#include <hip/hip_runtime.h>
#include <cstddef>

// Problem constants (hard-coded from reference):
// D=256, NH=8, NL=4, NP=4, DH=32, B=4, LV=5440, DFF=1024
// SHAPES = {64,64},{32,32},{16,16},{8,8}; level_start = {0,4096,5120,5376}
#define LVTOT  5440
#define MROWS  (4 * LVTOT)   // 21760 = 64 * 340 = 32 * 680; 5440 % 64 == 0

typedef __attribute__((ext_vector_type(8))) short short8;
typedef __attribute__((ext_vector_type(4))) float floatx4;

static __device__ __forceinline__ unsigned short f2bf(float f) {
    union { float f; unsigned int u; } v; v.f = f;
    unsigned int u = v.u;
    return (unsigned short)((u + 0x7FFFu + ((u >> 16) & 1u)) >> 16);   // RNE
}
static __device__ __forceinline__ float bf2f(unsigned short u) {
    union { unsigned int u; float f; } v; v.u = ((unsigned int)u) << 16; return v.f;
}
static __device__ __forceinline__ float bf2fs(short s) { return bf2f((unsigned short)s); }

// unpack-and-accumulate 8 bf16 channels from a 16B load with weight w
static __device__ __forceinline__ void macc8(float* acc, float w, const uint4& g) {
    #pragma unroll
    for (int d = 0; d < 4; ++d) {
        const unsigned u = (&g.x)[d];
        acc[2 * d]     = fmaf(w, __uint_as_float(u << 16), acc[2 * d]);
        acc[2 * d + 1] = fmaf(w, __uint_as_float(u & 0xffff0000u), acc[2 * d + 1]);
    }
}

// ---------------------------------------------------------------------------
// One-shot weight prep, all f32 [K][N] -> bf16 [N][K] at fixed slots:
//   val[0,65536) oa[65536,163840) (off rows 0..255 + attn rows 256..383)
//   out[163840,229376) ff1[229376,491520) ff2[491520,753664)
// plus bias_oa[384] floats (b_off ++ b_attn). Grid 2946x256.
// ---------------------------------------------------------------------------
__global__ __launch_bounds__(256) void prep_weights(
    const float* __restrict__ Wv, const float* __restrict__ Wo,
    const float* __restrict__ Wa, const float* __restrict__ Wu,
    const float* __restrict__ W1, const float* __restrict__ W2,
    const float* __restrict__ bo, const float* __restrict__ ba,
    unsigned short* __restrict__ wt, float* __restrict__ bias_oa)
{
    int idx = blockIdx.x * 256 + threadIdx.x;
    if (idx >= 754048) return;
    if (idx >= 753664) {               // bias concat
        int j = idx - 753664;
        bias_oa[j] = (j < 256) ? bo[j] : ba[j - 256];
        return;
    }
    float src;
    if (idx < 65536) {
        int r = idx; src = Wv[(size_t)(r & 255) * 256 + (r >> 8)];
    } else if (idx < 163840) {
        int r = idx - 65536; int n = r >> 8, k = r & 255;
        src = (n < 256) ? Wo[(size_t)k * 256 + n] : Wa[(size_t)k * 128 + (n - 256)];
    } else if (idx < 229376) {
        int r = idx - 163840; src = Wu[(size_t)(r & 255) * 256 + (r >> 8)];
    } else if (idx < 491520) {
        int r = idx - 229376; src = W1[(size_t)(r & 255) * 1024 + (r >> 8)];
    } else {
        int r = idx - 491520; src = W2[(size_t)(r & 1023) * 256 + (r >> 10)];
    }
    wt[idx] = f2bf(src);
}

// ---------------------------------------------------------------------------
// Reg-staged MFMA GEMM, padded LDS (conflict-free), 4 waves (2x2), BK=64.
// 64x64 tiles -> 18.4 KB LDS -> ~8 blocks/CU resident.
// SWZ=1: XCD-aware bijective remap (m204) + bn-fast tile order.
// HEADL=1 (val-proj): bf16 output remapped to per-head layout
//   [B][NH][LVTOT][32]  (x-adjacent sample cells 64B apart for msda pairing).
// ---------------------------------------------------------------------------
template<int AF32, int BM, int BN, int SPLITK, int RELU, int SWZ, int HEADL>
__global__ __launch_bounds__(256) void gemm_rs(
    const void* __restrict__ Av, const unsigned short* __restrict__ Bt,
    const float* __restrict__ bias,
    float* __restrict__ C, unsigned short* __restrict__ Cbf,
    int M, int N, int K)
{
    constexpr int AI = BM / 32;
    constexpr int BI = BN / 32;
    constexpr int FM = BM / 32;
    constexpr int FN = BN / 32;

    __shared__ short As[BM][72];
    __shared__ short Bs[BN][72];

    const int tid  = threadIdx.x;
    const int wave = tid >> 6;
    const int lane = tid & 63;
    const int ntiles = N / BN;

    int wgid;
    if (SWZ) {
        const int nwg = gridDim.x;
        const int xcd = blockIdx.x & 7;
        const int t   = blockIdx.x >> 3;
        const int q = nwg >> 3, r = nwg & 7;
        wgid = (xcd < r ? xcd * (q + 1) : r * (q + 1) + (xcd - r) * q) + t;
    } else {
        wgid = blockIdx.x;
    }
    const int tpm = ntiles * SPLITK;
    const int bm  = wgid / tpm;
    const int rem = wgid % tpm;
    const int bn  = rem % ntiles;
    const int ks  = rem / ntiles;

    const int row0 = bm * BM;
    const int col0 = bn * BN;
    const int Kper = K / SPLITK;
    const int kbeg = ks * Kper;

    const int wm = (wave >> 1) * (BM / 2);
    const int wn = (wave & 1) * (BN / 2);

    floatx4 acc[FM][FN];
    #pragma unroll
    for (int i = 0; i < FM; ++i)
        #pragma unroll
        for (int j = 0; j < FN; ++j)
            acc[i][j] = (floatx4){0.f, 0.f, 0.f, 0.f};

    const int lr = tid >> 3;
    const int lc = tid & 7;

    for (int k0 = 0; k0 < Kper; k0 += 64) {
        #pragma unroll
        for (int i = 0; i < AI; ++i) {
            const int r = lr + i * 32;
            if (AF32) {
                const float* Af = (const float*)Av;
                const float4 v0 = *reinterpret_cast<const float4*>(
                    &Af[(size_t)(row0 + r) * K + kbeg + k0 + lc * 8]);
                const float4 v1 = *reinterpret_cast<const float4*>(
                    &Af[(size_t)(row0 + r) * K + kbeg + k0 + lc * 8 + 4]);
                short8 s;
                s[0] = (short)f2bf(v0.x); s[1] = (short)f2bf(v0.y);
                s[2] = (short)f2bf(v0.z); s[3] = (short)f2bf(v0.w);
                s[4] = (short)f2bf(v1.x); s[5] = (short)f2bf(v1.y);
                s[6] = (short)f2bf(v1.z); s[7] = (short)f2bf(v1.w);
                *reinterpret_cast<short8*>(&As[r][lc * 8]) = s;
            } else {
                const unsigned short* Ab = (const unsigned short*)Av;
                *reinterpret_cast<short8*>(&As[r][lc * 8]) =
                    *reinterpret_cast<const short8*>(
                        &Ab[(size_t)(row0 + r) * K + kbeg + k0 + lc * 8]);
            }
        }
        #pragma unroll
        for (int i = 0; i < BI; ++i) {
            const int r = lr + i * 32;
            *reinterpret_cast<short8*>(&Bs[r][lc * 8]) =
                *reinterpret_cast<const short8*>(
                    &Bt[(size_t)(col0 + r) * K + kbeg + k0 + lc * 8]);
        }
        __syncthreads();

        #pragma unroll
        for (int kk = 0; kk < 64; kk += 32) {
            short8 af[FM], bfr[FN];
            #pragma unroll
            for (int i = 0; i < FM; ++i)
                af[i] = *reinterpret_cast<const short8*>(
                    &As[wm + i * 16 + (lane & 15)][kk + (lane >> 4) * 8]);
            #pragma unroll
            for (int j = 0; j < FN; ++j)
                bfr[j] = *reinterpret_cast<const short8*>(
                    &Bs[wn + j * 16 + (lane & 15)][kk + (lane >> 4) * 8]);
            #pragma unroll
            for (int i = 0; i < FM; ++i)
                #pragma unroll
                for (int j = 0; j < FN; ++j)
                    acc[i][j] = __builtin_amdgcn_mfma_f32_16x16x32_bf16(
                        af[i], bfr[j], acc[i][j], 0, 0, 0);
        }
        __syncthreads();
    }

    float* Cp = C ? C + (size_t)ks * M * N : nullptr;
    const int rbase = row0 + wm + (lane >> 4) * 4;
    const int cbase = col0 + wn + (lane & 15);
    const int bb_  = HEADL ? (row0 / LVTOT) : 0;   // whole tile in one batch
    #pragma unroll
    for (int j = 0; j < FN; ++j) {
        const float bj = (SPLITK == 1 || ks == 0) ? bias[cbase + j * 16] : 0.f;
        #pragma unroll
        for (int i = 0; i < FM; ++i) {
            #pragma unroll
            for (int r = 0; r < 4; ++r) {
                float v = acc[i][j][r] + bj;
                if (RELU) v = fmaxf(v, 0.f);
                if (HEADL) {
                    const int rr_ = rbase + i * 16 + r;
                    const int cc  = cbase + j * 16;
                    const size_t idx =
                        (((size_t)bb_ * 8 + (cc >> 5)) * LVTOT + (rr_ - bb_ * LVTOT)) * 32
                        + (cc & 31);
                    Cbf[idx] = f2bf(v);
                } else {
                    const size_t idx = (size_t)(rbase + i * 16 + r) * N + cbase + j * 16;
                    if (Cp)  Cp[idx] = v;
                    if (Cbf) Cbf[idx] = f2bf(v);
                }
            }
        }
    }
}

// ---------------------------------------------------------------------------
// GEMM + fused LayerNorm (full-row tile): BM=32, BN=256 (whole feature dim),
// 4 waves (2x2), wave tile 16x128, BK=64. LN in epilogue (shfl + LDS part).
// PREADD:  FF2+LN2 (res = qbuf);  POSTADD: out-proj+LN1 (res = value).
// ---------------------------------------------------------------------------
template<int PREADD, int POSTADD>
__global__ __launch_bounds__(256) void gemm_ln(
    const unsigned short* __restrict__ A, const unsigned short* __restrict__ Bt,
    const float* __restrict__ bias, const float* __restrict__ res,
    const float* __restrict__ g, const float* __restrict__ bta,
    float* __restrict__ outf, unsigned short* __restrict__ outbf,
    int K)
{
    __shared__ short As[32][72];
    __shared__ short Bs[256][72];
    __shared__ float2 part[2][32];

    const int tid  = threadIdx.x;
    const int wave = tid >> 6;
    const int lane = tid & 63;
    const int row0 = blockIdx.x * 32;
    const int wm = (wave >> 1) * 16;
    const int wn = (wave & 1) * 128;

    floatx4 acc[8];
    #pragma unroll
    for (int j = 0; j < 8; ++j) acc[j] = (floatx4){0.f, 0.f, 0.f, 0.f};

    const int lr = tid >> 3;
    const int lc = tid & 7;

    for (int k0 = 0; k0 < K; k0 += 64) {
        *reinterpret_cast<short8*>(&As[lr][lc * 8]) =
            *reinterpret_cast<const short8*>(
                &A[(size_t)(row0 + lr) * K + k0 + lc * 8]);
        #pragma unroll
        for (int i = 0; i < 8; ++i) {
            const int r = lr + i * 32;
            *reinterpret_cast<short8*>(&Bs[r][lc * 8]) =
                *reinterpret_cast<const short8*>(
                    &Bt[(size_t)r * K + k0 + lc * 8]);
        }
        __syncthreads();

        #pragma unroll
        for (int kk = 0; kk < 64; kk += 32) {
            short8 af = *reinterpret_cast<const short8*>(
                &As[wm + (lane & 15)][kk + (lane >> 4) * 8]);
            short8 bfr[8];
            #pragma unroll
            for (int j = 0; j < 8; ++j)
                bfr[j] = *reinterpret_cast<const short8*>(
                    &Bs[wn + j * 16 + (lane & 15)][kk + (lane >> 4) * 8]);
            #pragma unroll
            for (int j = 0; j < 8; ++j)
                acc[j] = __builtin_amdgcn_mfma_f32_16x16x32_bf16(
                    af, bfr[j], acc[j], 0, 0, 0);
        }
        __syncthreads();
    }

    const int rl = wm + (lane >> 4) * 4;
    const int cb = wn + (lane & 15);

    float v[8][4];
    #pragma unroll
    for (int j = 0; j < 8; ++j) {
        const float bj = bias[cb + j * 16];
        #pragma unroll
        for (int r = 0; r < 4; ++r) v[j][r] = acc[j][r] + bj;
    }
    if (PREADD) {
        #pragma unroll
        for (int j = 0; j < 8; ++j)
            #pragma unroll
            for (int r = 0; r < 4; ++r)
                v[j][r] += res[(size_t)(row0 + rl + r) * 256 + cb + j * 16];
    }

    float s1[4] = {0.f, 0.f, 0.f, 0.f}, s2[4] = {0.f, 0.f, 0.f, 0.f};
    #pragma unroll
    for (int j = 0; j < 8; ++j)
        #pragma unroll
        for (int r = 0; r < 4; ++r) {
            s1[r] += v[j][r];
            s2[r] += v[j][r] * v[j][r];
        }
    #pragma unroll
    for (int st = 1; st < 16; st <<= 1)
        #pragma unroll
        for (int r = 0; r < 4; ++r) {
            s1[r] += __shfl_xor(s1[r], st);
            s2[r] += __shfl_xor(s2[r], st);
        }
    if ((lane & 15) == 0) {
        #pragma unroll
        for (int r = 0; r < 4; ++r)
            part[wave & 1][rl + r] = (float2){s1[r], s2[r]};
    }
    __syncthreads();

    float mu[4], rstd[4];
    #pragma unroll
    for (int r = 0; r < 4; ++r) {
        const float2 p0 = part[0][rl + r];
        const float2 p1 = part[1][rl + r];
        const float t1 = p0.x + p1.x;
        const float t2 = p0.y + p1.y;
        mu[r] = t1 * (1.f / 256.f);
        rstd[r] = rsqrtf(t2 * (1.f / 256.f) - mu[r] * mu[r] + 1e-5f);
    }

    #pragma unroll
    for (int j = 0; j < 8; ++j) {
        const float gg = g[cb + j * 16];
        const float bb = bta[cb + j * 16];
        #pragma unroll
        for (int r = 0; r < 4; ++r) {
            const size_t idx = (size_t)(row0 + rl + r) * 256 + cb + j * 16;
            float o = (v[j][r] - mu[r]) * rstd[r] * gg + bb;
            if (POSTADD) o += res[idx];
            outf[idx] = o;
            if (outbf) outbf[idx] = f2bf(o);
        }
    }
}

// ---------------------------------------------------------------------------
// Deformable sampling + fused softmax, 2-phase LDS-staged.
// R18: per-head vproj layout [B][NH][LVTOT][32] + PAIRED gathers: phase 1
// emits per y-row {offset(base cell cA=clamp(xi,0,Nl-2)), wA, wB}; phase 2
// loads cells cA and cA+1 (64B apart -> one 128B span) — same VMEM count as
// R12 but half the cache-line touches. OOB weights exact 0; reads in-bounds.
// ---------------------------------------------------------------------------
__global__ __launch_bounds__(256) void msda_sample(
    const unsigned short* __restrict__ vproj,   // [B][8][LVTOT][32] bf16
    const unsigned short* __restrict__ oa,
    const float* __restrict__ refs,
    unsigned short* __restrict__ outbf)
{
    __shared__ uint4 meta[64][33];   // slot j: {byte_off, wA, wB, pad}

    const int tid = threadIdx.x;
    const int ul  = tid >> 2;
    const int u   = (blockIdx.x << 6) + ul;
    const int h   = u & 7;
    const int bq  = u >> 3;

    // ---------------- phase 1: coords (lane = unit*4 + level)
    {
        const int l   = tid & 3;
        const int sl  = 6 - l;
        const int Nl  = 1 << sl;
        const int msk = Nl - 1;
        const int lsi = (l == 0) ? 0 : (l == 1) ? 4096 : (l == 2) ? 5120 : 5376;

        const size_t oabase = (size_t)bq * 384;
        const short8  offv = *reinterpret_cast<const short8*>(oa + oabase + h * 32 + l * 8);
        const ushort4 lgu  = *reinterpret_cast<const ushort4*>(oa + oabase + 256 + h * 16 + l * 4);
        const float2  rr   = *reinterpret_cast<const float2*>(refs + (size_t)bq * 8 + l * 2);

        float lg0 = bf2f(lgu.x), lg1 = bf2f(lgu.y), lg2 = bf2f(lgu.z), lg3 = bf2f(lgu.w);
        float m = fmaxf(fmaxf(lg0, lg1), fmaxf(lg2, lg3));
        m = fmaxf(m, __shfl_xor(m, 1));
        m = fmaxf(m, __shfl_xor(m, 2));
        float e0 = __expf(lg0 - m), e1 = __expf(lg1 - m),
              e2 = __expf(lg2 - m), e3 = __expf(lg3 - m);
        float s = e0 + e1 + e2 + e3;
        s += __shfl_xor(s, 1);
        s += __shfl_xor(s, 2);
        const float inv = 1.f / s;
        const float aw4[4] = {e0 * inv, e1 * inv, e2 * inv, e3 * inv};

        const float Nf = (float)Nl;
        #pragma unroll
        for (int p = 0; p < 4; ++p) {
            const float ox = bf2fs(offv[p * 2 + 0]);
            const float oy = bf2fs(offv[p * 2 + 1]);
            const float aw = aw4[p];
            const float x = fmaf(rr.x, Nf, ox) - 0.5f;
            const float y = fmaf(rr.y, Nf, oy) - 0.5f;
            const float xf = floorf(x), yf = floorf(y);
            const float tx = x - xf, ty = y - yf;
            const int xi = (int)xf, yi = (int)yf;
            const bool y0v = (unsigned)yi < (unsigned)Nl;
            const bool y1v = (unsigned)(yi + 1) < (unsigned)Nl;
            const float w0x = (1.f - tx) * aw, w1x = tx * aw;

            // x-pair: base cell cA = clamp(xi, 0, Nl-2); cells (cA, cA+1)
            const int cA = min(max(xi, 0), Nl - 2);
            float wxA = 0.f, wxB = 0.f;
            if (cA == xi)          { wxA = w0x; wxB = w1x; }   // normal
            else if (cA == xi + 1) { wxA = w1x; }              // xi == -1
            else if (cA + 1 == xi) { wxB = w0x; }              // xi == Nl-1
            const float wy0 = y0v ? (1.f - ty) : 0.f;
            const float wy1 = y1v ? ty : 0.f;

            const int ym0 = (yi & msk) << sl, ym1 = ((yi + 1) & msk) << sl;
            uint4 m0, m1;
            m0.x = (unsigned)((lsi + ym0 + cA) << 6);   // 64B cells
            m0.y = __float_as_uint(wxA * wy0);
            m0.z = __float_as_uint(wxB * wy0);
            m0.w = 0;
            m1.x = (unsigned)((lsi + ym1 + cA) << 6);
            m1.y = __float_as_uint(wxA * wy1);
            m1.z = __float_as_uint(wxB * wy1);
            m1.w = 0;
            meta[ul][l * 8 + p * 2 + 0] = m0;
            meta[ul][l * 8 + p * 2 + 1] = m1;
        }
    }
    __syncthreads();

    // ---------------- phase 2: paired gathers + MAC (lane = unit*4 + chunk)
    const int c = tid & 3;
    const int b = bq / LVTOT;
    const char* vbb = (const char*)(vproj
        + ((size_t)(b * 8 + h)) * LVTOT * 32 + c * 8);

    float acc[8] = {0.f, 0.f, 0.f, 0.f, 0.f, 0.f, 0.f, 0.f};
    #pragma unroll 4
    for (int j = 0; j < 32; ++j) {
        const uint4 mt = meta[ul][j];
        const uint4 gA = *reinterpret_cast<const uint4*>(vbb + mt.x);
        const uint4 gB = *reinterpret_cast<const uint4*>(vbb + mt.x + 64);
        macc8(acc, __uint_as_float(mt.y), gA);
        macc8(acc, __uint_as_float(mt.z), gB);
    }

    uint4 ov;
    ov.x = (unsigned)f2bf(acc[0]) | ((unsigned)f2bf(acc[1]) << 16);
    ov.y = (unsigned)f2bf(acc[2]) | ((unsigned)f2bf(acc[3]) << 16);
    ov.z = (unsigned)f2bf(acc[4]) | ((unsigned)f2bf(acc[5]) << 16);
    ov.w = (unsigned)f2bf(acc[6]) | ((unsigned)f2bf(acc[7]) << 16);
    *reinterpret_cast<uint4*>(outbf + (size_t)bq * 256 + h * 32 + c * 8) = ov;
}

// ---------------------------------------------------------------------------
extern "C" void kernel_launch(void* const* d_in, const int* in_sizes, int n_in,
                              void* d_out, int out_size, void* d_ws, size_t ws_size,
                              hipStream_t stream)
{
    const float* query  = (const float*)d_in[0];
    const float* refs   = (const float*)d_in[1];
    const float* value  = (const float*)d_in[2];
    const float* W_off  = (const float*)d_in[5];
    const float* b_off  = (const float*)d_in[6];
    const float* W_attn = (const float*)d_in[7];
    const float* b_attn = (const float*)d_in[8];
    const float* W_val  = (const float*)d_in[9];
    const float* b_val  = (const float*)d_in[10];
    const float* W_out  = (const float*)d_in[11];
    const float* b_out  = (const float*)d_in[12];
    const float* ln1g   = (const float*)d_in[13];
    const float* ln1b   = (const float*)d_in[14];
    const float* ln2g   = (const float*)d_in[15];
    const float* ln2b   = (const float*)d_in[16];
    const float* W_ff1  = (const float*)d_in[17];
    const float* b_ff1  = (const float*)d_in[18];
    const float* W_ff2  = (const float*)d_in[19];
    const float* b_ff2  = (const float*)d_in[20];
    float* out = (float*)d_out;
    float* ws  = (float*)d_ws;

    const size_t R = (size_t)MROWS * 256;   // 5,570,560 floats
    // Workspace (float offsets), lifetime-reused:
    unsigned short* wt_base = (unsigned short*)ws;         // 753,664 bf16
    float* bias_oa = ws + 376832;                          // 384 (pad to 512)
    const size_t base0 = 377344;
    unsigned short* oa_bf    = (unsigned short*)(ws + base0);              // 0.75R fl
    unsigned short* vproj_bf = (unsigned short*)(ws + base0 + 3 * R / 4);  // 0.5R fl
    unsigned short* msda_bf  = (unsigned short*)(ws + base0 + 5 * R / 4);  // 0.5R fl
    // f1 pad: [base0+1.75R, base0+2R)
    float* qbuf = ws + base0 + 2 * R;                       // R
    unsigned short* qbuf_bf = (unsigned short*)(ws + base0 + 3 * R);       // 0.5R fl
    unsigned short* f1_bf = oa_bf;   // spans [base0, base0+2R) over dead regions

    unsigned short* wt_val = wt_base;
    unsigned short* wt_oa  = wt_base + 65536;
    unsigned short* wt_out = wt_base + 163840;
    unsigned short* wt_ff1 = wt_base + 229376;
    unsigned short* wt_ff2 = wt_base + 491520;

    const dim3 blk(256);
    const int mt64 = MROWS / 64;    // 340
    const int mt32 = MROWS / 32;    // 680

    // 0: weight prep
    prep_weights<<<dim3(2946), blk, 0, stream>>>(W_val, W_off, W_attn, W_out,
                                                 W_ff1, W_ff2, b_off, b_attn,
                                                 wt_base, bias_oa);
    // 1: value projection (f32 A) -> per-head bf16 layout, 1360 blocks
    gemm_rs<1, 64, 64, 1, 0, 1, 1><<<dim3(mt64 * 4), blk, 0, stream>>>(
        value, wt_val, b_val, nullptr, vproj_bf, MROWS, 256, 256);
    // 2: merged offsets+logits projection (f32 A), 64x64 -> 2040 blocks
    gemm_rs<1, 64, 64, 1, 0, 1, 0><<<dim3(mt64 * 6), blk, 0, stream>>>(
        query, wt_oa, bias_oa, nullptr, oa_bf, MROWS, 384, 256);
    // 3: sampling (paired gathers; 64 units/block -> 2720 blocks)
    msda_sample<<<dim3(MROWS * 8 / 64), blk, 0, stream>>>(vproj_bf, oa_bf, refs, msda_bf);
    // 4: out-proj + LN1 fused: q = value + LN(msda@Wout+b)
    gemm_ln<0, 1><<<dim3(mt32), blk, 0, stream>>>(
        msda_bf, wt_out, b_out, value, ln1g, ln1b, qbuf, qbuf_bf, 256);
    // 5: f1 = relu(q @ W_ff1), 64x64 -> 5440 blocks
    gemm_rs<0, 64, 64, 1, 1, 1, 0><<<dim3(mt64 * 16), blk, 0, stream>>>(
        qbuf_bf, wt_ff1, b_ff1, nullptr, f1_bf, MROWS, 1024, 256);
    // 6: FF2 + LN2 fused: out = LN(qbuf + f1@Wff2 + b)
    gemm_ln<1, 0><<<dim3(mt32), blk, 0, stream>>>(
        f1_bf, wt_ff2, b_ff2, qbuf, ln2g, ln2b, out, nullptr, 1024);
}